// Round 2
// baseline (203.114 us; speedup 1.0000x reference)
//
#include <hip/hip_runtime.h>
#include <hip/hip_bf16.h>

// Problem constants
#define N_TOK 16384
#define CIN   512
#define COUT  512
#define NE    8
// GEMM tile config (m97-style 128x128, BK=64, 4 waves)
#define BM    128
#define BN    128
#define BK    64
#define KT_PER_E (CIN / BK)        // 8 k-tiles per expert
#define KTILES   (NE * KT_PER_E)   // 64 total k-tiles

typedef __attribute__((ext_vector_type(8))) short bf16x8;
typedef __attribute__((ext_vector_type(4))) float f32x4;

__device__ __forceinline__ short f2bf(float f) {
  unsigned u = __builtin_bit_cast(unsigned, f);
  u += 0x7FFFu + ((u >> 16) & 1u);   // RNE
  return (short)(u >> 16);
}

// f32 -> bf16 conversion, 8 elements per thread
__global__ void cvt_f32_bf16(const float* __restrict__ in, short* __restrict__ out, int n8) {
  int i = blockIdx.x * blockDim.x + threadIdx.x;
  if (i >= n8) return;
  const float4* p = (const float4*)in + (size_t)i * 2;
  float4 a = p[0], b = p[1];
  bf16x8 o;
  o[0] = f2bf(a.x); o[1] = f2bf(a.y); o[2] = f2bf(a.z); o[3] = f2bf(a.w);
  o[4] = f2bf(b.x); o[5] = f2bf(b.y); o[6] = f2bf(b.z); o[7] = f2bf(b.w);
  ((bf16x8*)out)[i] = o;
}

__device__ __forceinline__ void async16(short* lds, const short* g) {
  __builtin_amdgcn_global_load_lds(
      (const __attribute__((address_space(1))) void*)g,
      (__attribute__((address_space(3))) void*)lds, 16, 0, 0);
}

// out[n,o] = sum_e coef[n,e] * sum_i x[n,i]*W[e,o,i]  +  sum_e coef[n,e]*bias[e,o]
__global__ __launch_bounds__(256, 2)
void moe_gemm(const short* __restrict__ xb,    // [N_TOK][CIN] bf16
              const short* __restrict__ wb,    // [NE][COUT][CIN] bf16
              const float* __restrict__ coef,  // [N_TOK][NE] f32
              const float* __restrict__ bias,  // [NE][COUT] f32
              float* __restrict__ out) {       // [N_TOK][COUT] f32
  __shared__ short As[2][BM * BK];
  __shared__ short Bs[2][BN * BK];
  __shared__ float cf[BM * NE];

  const int tid  = threadIdx.x;
  const int lane = tid & 63;
  const int wid  = tid >> 6;   // 0..3
  const int wr   = wid >> 1;   // wave row 0..1 (64-row slab)
  const int wc   = wid & 1;    // wave col 0..1 (64-col slab)
  const int lhi  = lane >> 4;  // 0..3
  const int llo  = lane & 15;

  const int bid  = blockIdx.x;
  const int ct   = bid & 3;          // 512/128 = 4 col tiles
  const int rt   = bid >> 2;
  const int row0 = rt * BM;
  const int col0 = ct * BN;

  // stage this block's coef rows: 128 x 8 f32 = 4KB, contiguous in memory
  ((float4*)cf)[tid] = ((const float4*)(coef + row0 * NE))[tid];

  // staging geometry: 256 threads x 16B = 4KB/pass, 4 passes per 16KB tile
  const int r_st = tid >> 3;          // 0..31
  const int c_st = (tid & 7) * 8;     // k-elem offset
  const short* gA     = xb + (row0 + r_st) * CIN + c_st;
  const short* gBbase = wb + (col0 + r_st) * CIN + c_st;

  // MFMA fragment LDS element offsets (row-major [rows][BK])
  const int aoff = (wr * 64 + llo) * BK + lhi * 8;
  const int boff = (wc * 64 + llo) * BK + lhi * 8;

  auto STAGE = [&](int buf, int t) {
    const int e  = t >> 3;
    const int i0 = (t & 7) * BK;
    const short* ga = gA + i0;
    const short* gb = gBbase + e * (CIN * COUT) + i0;
    short* la = &As[buf][tid * 8];
    short* lb = &Bs[buf][tid * 8];
#pragma unroll
    for (int p = 0; p < 4; ++p) {
      async16(la + p * 2048, ga + p * 32 * CIN);
      async16(lb + p * 2048, gb + p * 32 * CIN);
    }
  };

  f32x4 accO[4][4];
#pragma unroll
  for (int m = 0; m < 4; ++m)
#pragma unroll
    for (int n = 0; n < 4; ++n)
      accO[m][n] = (f32x4){0.f, 0.f, 0.f, 0.f};

  STAGE(0, 0);
  __syncthreads();   // drains vmcnt; also covers the cf writes

  int cur = 0, t = 0;
  for (int e = 0; e < NE; ++e) {
    f32x4 accE[4][4];
#pragma unroll
    for (int m = 0; m < 4; ++m)
#pragma unroll
      for (int n = 0; n < 4; ++n)
        accE[m][n] = (f32x4){0.f, 0.f, 0.f, 0.f};

    for (int kt = 0; kt < KT_PER_E; ++kt, ++t) {
      if (t + 1 < KTILES) STAGE(cur ^ 1, t + 1);
      const short* Ab = As[cur];
      const short* Bb = Bs[cur];
#pragma unroll
      for (int ks = 0; ks < 2; ++ks) {
        bf16x8 af[4], bfr[4];
#pragma unroll
        for (int m = 0; m < 4; ++m)
          af[m] = *(const bf16x8*)&Ab[aoff + m * (16 * BK) + ks * 32];
#pragma unroll
        for (int n = 0; n < 4; ++n)
          bfr[n] = *(const bf16x8*)&Bb[boff + n * (16 * BK) + ks * 32];
#pragma unroll
        for (int m = 0; m < 4; ++m)
#pragma unroll
          for (int n = 0; n < 4; ++n)
            accE[m][n] = __builtin_amdgcn_mfma_f32_16x16x32_bf16(af[m], bfr[n], accE[m][n], 0, 0, 0);
      }
      __syncthreads();   // vmcnt(0)+lgkmcnt(0)+barrier: next buffer ready, this one free
      cur ^= 1;
    }

    // expert boundary: accO += coef[n,e] * accE   (C/D row = lhi*4+reg)
#pragma unroll
    for (int m = 0; m < 4; ++m)
#pragma unroll
      for (int r = 0; r < 4; ++r) {
        float c = cf[(wr * 64 + m * 16 + lhi * 4 + r) * NE + e];
#pragma unroll
        for (int n = 0; n < 4; ++n)
          accO[m][n][r] += c * accE[m][n][r];
      }
  }

  // epilogue: out = accO + sum_e coef[n,e]*bias[e,o]
  float bv[4][NE];
#pragma unroll
  for (int n = 0; n < 4; ++n) {
    int cg = col0 + wc * 64 + n * 16 + llo;
#pragma unroll
    for (int e = 0; e < NE; ++e) bv[n][e] = bias[e * COUT + cg];
  }
#pragma unroll
  for (int m = 0; m < 4; ++m)
#pragma unroll
    for (int r = 0; r < 4; ++r) {
      int row_l = wr * 64 + m * 16 + lhi * 4 + r;
      const float* cp = &cf[row_l * NE];
      float c0 = cp[0], c1 = cp[1], c2 = cp[2], c3 = cp[3],
            c4 = cp[4], c5 = cp[5], c6 = cp[6], c7 = cp[7];
      float* orow = out + (size_t)(row0 + row_l) * COUT;
#pragma unroll
      for (int n = 0; n < 4; ++n) {
        int cg = col0 + wc * 64 + n * 16 + llo;
        float bm = c0 * bv[n][0] + c1 * bv[n][1] + c2 * bv[n][2] + c3 * bv[n][3]
                 + c4 * bv[n][4] + c5 * bv[n][5] + c6 * bv[n][6] + c7 * bv[n][7];
        orow[cg] = accO[m][n][r] + bm;
      }
    }
}

extern "C" void kernel_launch(void* const* d_in, const int* in_sizes, int n_in,
                              void* d_out, int out_size, void* d_ws, size_t ws_size,
                              hipStream_t stream) {
  const float* x    = (const float*)d_in[0];  // [16384][512]
  const float* coef = (const float*)d_in[1];  // [16384][8]
  const float* w    = (const float*)d_in[2];  // [8][512][512]
  const float* bias = (const float*)d_in[3];  // [8][512]
  float* out = (float*)d_out;

  short* xb = (short*)d_ws;                          // 16 MB bf16 x
  short* wb = xb + (size_t)N_TOK * CIN;              // 4 MB bf16 weight

  cvt_f32_bf16<<<(N_TOK * CIN / 8) / 256, 256, 0, stream>>>(x, xb, N_TOK * CIN / 8);
  cvt_f32_bf16<<<(NE * COUT * CIN / 8) / 256, 256, 0, stream>>>(w, wb, NE * COUT * CIN / 8);

  moe_gemm<<<(N_TOK / BM) * (COUT / BN), 256, 0, stream>>>(xb, wb, coef, bias, out);
}

// Round 3
// 192.497 us; speedup vs baseline: 1.0552x; 1.0552x over previous
//
#include <hip/hip_runtime.h>

// Problem constants
#define N_TOK 16384
#define CIN   512
#define COUT  512
#define NE    8
// 8-phase schedule, 256x128 tile, BK=64, 8 waves (2M x 4N), triple-buffered LDS
#define BM    256
#define BN    128
#define BK    64
#define KTILES   64        // 8 experts x 8 k-chunks

typedef __attribute__((ext_vector_type(8))) short bf16x8;
typedef __attribute__((ext_vector_type(4))) short s16x4;
typedef __attribute__((ext_vector_type(4))) float f32x4;

__device__ __forceinline__ short f2bf(float f) {
  unsigned u = __builtin_bit_cast(unsigned, f);
  u += 0x7FFFu + ((u >> 16) & 1u);   // RNE
  return (short)(u >> 16);
}

// fused f32->bf16 for x and w, 4 floats/thread, fully coalesced
__global__ void cvt_all(const float4* __restrict__ x, const float4* __restrict__ w,
                        s16x4* __restrict__ xb, s16x4* __restrict__ wb) {
  int i = blockIdx.x * blockDim.x + threadIdx.x;
  const int NX = N_TOK * CIN / 4;          // 2,097,152 groups
  float4 v; s16x4* o;
  if (i < NX) { v = x[i]; o = xb + i; }
  else       { int j = i - NX; v = w[j]; o = wb + j; }
  s16x4 r;
  r[0] = f2bf(v.x); r[1] = f2bf(v.y); r[2] = f2bf(v.z); r[3] = f2bf(v.w);
  *o = r;
}

__device__ __forceinline__ void async16(short* lds, const short* g) {
  __builtin_amdgcn_global_load_lds(
      (const __attribute__((address_space(1))) void*)g,
      (__attribute__((address_space(3))) void*)lds, 16, 0, 0);
}

// out[n,o] = sum_e coef[n,e] * sum_i x[n,i]*W[e,o,i] + sum_e coef[n,e]*bias[e,o]
__global__ __launch_bounds__(512, 2)
void moe_gemm(const short* __restrict__ xb,    // [N_TOK][CIN] bf16
              const short* __restrict__ wb,    // [NE][COUT][CIN] bf16
              const float* __restrict__ coef,  // [N_TOK][NE] f32
              const float* __restrict__ bias,  // [NE][COUT] f32
              float* __restrict__ out) {       // [N_TOK][COUT] f32
  __shared__ short As[3][BM * BK];   // 3 x 32KB
  __shared__ short Bs[3][BN * BK];   // 3 x 16KB
  __shared__ float cf[BM * NE];      // 8KB   (total 152KB -> 1 block/CU)

  const int tid  = threadIdx.x;
  const int lane = tid & 63;
  const int wid  = tid >> 6;   // 0..7
  const int wm   = wid >> 2;   // 0..1  (128-row slab)
  const int wn   = wid & 3;    // 0..3  (32-col slab)
  const int lhi  = lane >> 4;  // 0..3
  const int llo  = lane & 15;

  const int bid  = blockIdx.x;
  const int ct   = bid & 3;          // 512/128 = 4 col tiles
  const int rt   = bid >> 2;         // 64 row tiles
  const int row0 = rt * BM;
  const int col0 = ct * BN;

  // coef tile: 256 rows x 8 f32 = 8KB, 512 thr x float4
  ((float4*)cf)[tid] = ((const float4*)(coef + row0 * NE))[tid];

  // ---- staging geometry: pass = 512 thr x 16B = 8KB = 64 rows x 64k
  // T2 swizzle (both-sides XOR, involution): LDS stays linear for gload_lds;
  // SOURCE col is pre-swizzled; reads apply the same XOR.
  const int r_st = tid >> 3;                               // 0..63
  const int c_sw = ((tid & 7) * 8) ^ ((r_st & 7) << 3);    // swizzled col (shorts)
  const short* gA = xb + (row0 + r_st) * CIN + c_sw;
  const short* gB = wb + (col0 + r_st) * CIN + c_sw;

  auto stageA = [&](int buf, int t, int p) {   // p = 0..3
    const int i0 = (t & 7) * BK;
    async16(&As[buf][p * 4096 + tid * 8], gA + p * 64 * CIN + i0);
  };
  auto stageB = [&](int buf, int t, int p) {   // p = 0..1
    const int e  = t >> 3;
    const int i0 = (t & 7) * BK;
    async16(&Bs[buf][p * 4096 + tid * 8], gB + e * (CIN * COUT) + p * 64 * CIN + i0);
  };

  // fragment read offsets: row*64 + ((ks*32 + lhi*8) ^ ((row&7)<<3)), row&7 == llo&7
  const int swz0 = (lhi * 8) ^ ((llo & 7) << 3);         // ks=0
  const int swz1 = (32 + lhi * 8) ^ ((llo & 7) << 3);    // ks=1
  const int arow = wm * 128 + llo;                       // + m*16
  const int brow = wn * 32 + llo;                        // + n*16

  f32x4 accO[8][2], accE[8][2];
#pragma unroll
  for (int m = 0; m < 8; ++m)
#pragma unroll
    for (int n = 0; n < 2; ++n) {
      accO[m][n] = (f32x4){0.f, 0.f, 0.f, 0.f};
      accE[m][n] = (f32x4){0.f, 0.f, 0.f, 0.f};
    }

  // ---- prologue: stage tiles 0,1 (6 loads each); wait for tile 0 only
#pragma unroll
  for (int p = 0; p < 4; ++p) stageA(0, 0, p);
#pragma unroll
  for (int p = 0; p < 2; ++p) stageB(0, 0, p);
#pragma unroll
  for (int p = 0; p < 4; ++p) stageA(1, 1, p);
#pragma unroll
  for (int p = 0; p < 2; ++p) stageB(1, 1, p);
  asm volatile("s_waitcnt vmcnt(6) lgkmcnt(0)");   // tile0 landed + cf visible
  __builtin_amdgcn_s_barrier();

  bf16x8 bfr[2][2];   // B frags persist across the 4 phases of a tile

  for (int t = 0; t < KTILES; ++t) {
    const int cur = t % 3;
    const int nx  = (t + 2) % 3;
    const bool pf = (t + 2) < KTILES;
    const short* Ab = As[cur];
    const short* Bb = Bs[cur];

#pragma unroll
    for (int p = 0; p < 4; ++p) {
      // ds-load this phase's A frags (m = 2p, 2p+1); phase 0 also loads B frags
      bf16x8 af[2][2];
      af[0][0] = *(const bf16x8*)&Ab[(arow + (2 * p) * 16) * 64 + swz0];
      af[0][1] = *(const bf16x8*)&Ab[(arow + (2 * p) * 16) * 64 + swz1];
      af[1][0] = *(const bf16x8*)&Ab[(arow + (2 * p + 1) * 16) * 64 + swz0];
      af[1][1] = *(const bf16x8*)&Ab[(arow + (2 * p + 1) * 16) * 64 + swz1];
      if (p == 0) {
        bfr[0][0] = *(const bf16x8*)&Bb[(brow + 0) * 64 + swz0];
        bfr[0][1] = *(const bf16x8*)&Bb[(brow + 0) * 64 + swz1];
        bfr[1][0] = *(const bf16x8*)&Bb[(brow + 16) * 64 + swz0];
        bfr[1][1] = *(const bf16x8*)&Bb[(brow + 16) * 64 + swz1];
      }
      // issue next-next tile's staging, spread across phases (counted, never drained here)
      if (pf) {
        if (p == 0)      { stageA(nx, t + 2, 0); stageA(nx, t + 2, 1); }
        else if (p == 1) { stageA(nx, t + 2, 2); stageA(nx, t + 2, 3); }
        else if (p == 2) { stageB(nx, t + 2, 0); stageB(nx, t + 2, 1); }
      }
      __builtin_amdgcn_s_barrier();
      asm volatile("s_waitcnt lgkmcnt(0)");
      __builtin_amdgcn_s_setprio(1);
#pragma unroll
      for (int mm = 0; mm < 2; ++mm)
#pragma unroll
        for (int n = 0; n < 2; ++n)
#pragma unroll
          for (int ks = 0; ks < 2; ++ks)
            accE[2 * p + mm][n] = __builtin_amdgcn_mfma_f32_16x16x32_bf16(
                af[mm][ks], bfr[n][ks], accE[2 * p + mm][n], 0, 0, 0);
      __builtin_amdgcn_s_setprio(0);
      __builtin_amdgcn_s_barrier();
    }

    // expert boundary: accO += coef[row,e] * accE (C/D row = lhi*4+reg), overlap with load wait
    if ((t & 7) == 7) {
      const int e = t >> 3;
#pragma unroll
      for (int m = 0; m < 8; ++m)
#pragma unroll
        for (int r = 0; r < 4; ++r) {
          float c = cf[(wm * 128 + m * 16 + lhi * 4 + r) * NE + e];
#pragma unroll
          for (int n = 0; n < 2; ++n) {
            accO[m][n][r] += c * accE[m][n][r];
            accE[m][n][r] = 0.f;
          }
        }
    }

    // tile boundary: counted vmcnt — tile t+1's 6 loads done, t+2's 6 may stay in flight
    if (t < KTILES - 2) {
      asm volatile("s_waitcnt vmcnt(6)");
      __builtin_amdgcn_s_barrier();
    } else if (t == KTILES - 2) {
      asm volatile("s_waitcnt vmcnt(0)");
      __builtin_amdgcn_s_barrier();
    }
    // t == KTILES-1: fall through to epilogue
  }

  // ---- epilogue: out = accO + sum_e coef[n,e]*bias[e,o]
  float bcol[2][NE];
#pragma unroll
  for (int n = 0; n < 2; ++n) {
    const int cg = col0 + wn * 32 + n * 16 + llo;
#pragma unroll
    for (int e = 0; e < NE; ++e) bcol[n][e] = bias[e * COUT + cg];
  }
#pragma unroll
  for (int m = 0; m < 8; ++m)
#pragma unroll
    for (int r = 0; r < 4; ++r) {
      const int rl = wm * 128 + m * 16 + lhi * 4 + r;
      float cv[NE];
#pragma unroll
      for (int e = 0; e < NE; ++e) cv[e] = cf[rl * NE + e];
      float* orow = out + (size_t)(row0 + rl) * COUT;
#pragma unroll
      for (int n = 0; n < 2; ++n) {
        float bm = 0.f;
#pragma unroll
        for (int e = 0; e < NE; ++e) bm += cv[e] * bcol[n][e];
        orow[col0 + wn * 32 + n * 16 + llo] = accO[m][n][r] + bm;
      }
    }
}

extern "C" void kernel_launch(void* const* d_in, const int* in_sizes, int n_in,
                              void* d_out, int out_size, void* d_ws, size_t ws_size,
                              hipStream_t stream) {
  const float* x    = (const float*)d_in[0];  // [16384][512]
  const float* coef = (const float*)d_in[1];  // [16384][8]
  const float* w    = (const float*)d_in[2];  // [8][512][512]
  const float* bias = (const float*)d_in[3];  // [8][512]
  float* out = (float*)d_out;

  short* xb = (short*)d_ws;                   // 16 MB bf16 x
  short* wb = xb + (size_t)N_TOK * CIN;       // 4 MB bf16 weight

  const int NX = N_TOK * CIN / 4, NW = NE * COUT * CIN / 4;
  cvt_all<<<(NX + NW) / 256, 256, 0, stream>>>(
      (const float4*)x, (const float4*)w, (s16x4*)xb, (s16x4*)wb);

  moe_gemm<<<(N_TOK / BM) * (COUT / BN), 512, 0, stream>>>(xb, wb, coef, bias, out);
}

// Round 4
// 183.557 us; speedup vs baseline: 1.1065x; 1.0487x over previous
//
#include <hip/hip_runtime.h>

// Problem constants
#define N_TOK 16384
#define CIN   512
#define COUT  512
#define NE    8
// 256x128 tile, BK=64, 8 waves (4M x 2N) -> 64x64 per wave, 2 phases x 16 MFMA
#define BM    256
#define BN    128
#define BK    64
#define KTILES 64        // 8 experts x 8 k-chunks

typedef __attribute__((ext_vector_type(8))) short bf16x8;
typedef __attribute__((ext_vector_type(4))) short s16x4;
typedef __attribute__((ext_vector_type(4))) float f32x4;

__device__ __forceinline__ short f2bf(float f) {
  unsigned u = __builtin_bit_cast(unsigned, f);
  u += 0x7FFFu + ((u >> 16) & 1u);   // RNE
  return (short)(u >> 16);
}

// fused f32->bf16 for x and w, 4 floats/thread, fully coalesced
__global__ void cvt_all(const float4* __restrict__ x, const float4* __restrict__ w,
                        s16x4* __restrict__ xb, s16x4* __restrict__ wb) {
  int i = blockIdx.x * blockDim.x + threadIdx.x;
  const int NX = N_TOK * CIN / 4;
  float4 v; s16x4* o;
  if (i < NX) { v = x[i]; o = xb + i; }
  else       { int j = i - NX; v = w[j]; o = wb + j; }
  s16x4 r;
  r[0] = f2bf(v.x); r[1] = f2bf(v.y); r[2] = f2bf(v.z); r[3] = f2bf(v.w);
  *o = r;
}

__device__ __forceinline__ void async16(short* lds, const short* g) {
  __builtin_amdgcn_global_load_lds(
      (const __attribute__((address_space(1))) void*)g,
      (__attribute__((address_space(3))) void*)lds, 16, 0, 0);
}

// out[n,o] = sum_e coef[n,e] * sum_i x[n,i]*W[e,o,i] + sum_e coef[n,e]*bias[e,o]
// Single accumulator via Horner rescaling: acc holds (sum_{e'<=e} c_e' S_e') / c_e.
__global__ __launch_bounds__(512, 2)
void moe_gemm(const short* __restrict__ xb,    // [N_TOK][CIN] bf16
              const short* __restrict__ wb,    // [NE][COUT][CIN] bf16
              const float* __restrict__ coef,  // [N_TOK][NE] f32
              const float* __restrict__ bias,  // [NE][COUT] f32
              float* __restrict__ out) {       // [N_TOK][COUT] f32
  __shared__ short As[2][BM * BK];   // 2 x 32KB
  __shared__ short Bs[2][BN * BK];   // 2 x 16KB
  __shared__ float cfc[BM * NE];     // 8KB raw coef (epilogue bias mix)
  __shared__ float cfr[BM * NE];     // 8KB Horner ratios

  const int tid  = threadIdx.x;
  const int lane = tid & 63;
  const int wid  = tid >> 6;   // 0..7
  const int wm   = wid >> 1;   // 0..3  (64-row slab)
  const int wn   = wid & 1;    // 0..1  (64-col slab)
  const int lhi  = lane >> 4;  // 0..3
  const int llo  = lane & 15;

  // XCD-chunked swizzle: 256 blocks = 8 XCDs x 32 contiguous
  const int bid0 = blockIdx.x;
  const int bid  = (bid0 & 7) * 32 + (bid0 >> 3);
  const int ct   = bid & 3;          // 4 col tiles
  const int rt   = bid >> 2;         // 64 row tiles
  const int row0 = rt * BM;
  const int col0 = ct * BN;

  // coef tile: 256 rows x 8 f32 = 8KB, 512 thr x float4
  ((float4*)cfc)[tid] = ((const float4*)(coef + row0 * NE))[tid];

  // staging: pass = 512 thr x 16B = 8KB = 64 rows x 64k. T2 both-sides XOR swizzle:
  // LDS dest linear (gload_lds requirement), SOURCE col pre-swizzled, reads re-apply XOR.
  const int r_st = tid >> 3;                               // 0..63
  const int c_sw = ((tid & 7) * 8) ^ ((r_st & 7) << 3);    // swizzled col (shorts)
  const short* gA = xb + (size_t)(row0 + r_st) * CIN + c_sw;
  const short* gB = wb + (size_t)(col0 + r_st) * CIN + c_sw;

  auto stage = [&](int buf, int t) {   // 6 gloads: A 4 passes + B 2 passes
    const int e  = t >> 3;
    const int i0 = (t & 7) * BK;
#pragma unroll
    for (int p = 0; p < 4; ++p)
      async16(&As[buf][p * 4096 + tid * 8], gA + p * 64 * CIN + i0);
#pragma unroll
    for (int p = 0; p < 2; ++p)
      async16(&Bs[buf][p * 4096 + tid * 8], gB + (size_t)e * (CIN * COUT) + p * 64 * CIN + i0);
  };

  // ---- prologue
  stage(0, 0);
  asm volatile("s_waitcnt lgkmcnt(0)");   // cfc stores visible
  __builtin_amdgcn_s_barrier();
  if (tid < BM) {                         // Horner ratio table, one thread per row
    const float* cp = &cfc[tid * NE];
    float c[NE];
#pragma unroll
    for (int e = 0; e < NE; ++e) c[e] = fmaxf(cp[e], 1e-20f);
    float* rp = &cfr[tid * NE];
#pragma unroll
    for (int e = 0; e < NE - 1; ++e) rp[e] = c[e] / c[e + 1];
    rp[NE - 1] = c[NE - 1];
  }
  asm volatile("s_waitcnt vmcnt(0) lgkmcnt(0)");   // tile0 staged + cfr visible
  __builtin_amdgcn_s_barrier();

  // fragment read offsets: element [row][col] lives at [row][col ^ ((row&7)<<3)]
  const int swz0 = (lhi * 8) ^ ((llo & 7) << 3);
  const int swz1 = (32 + lhi * 8) ^ ((llo & 7) << 3);
  const int arow = wm * 64 + llo;
  const int brow = wn * 64 + llo;

  f32x4 acc[4][4];   // [m][n], 64 VGPR
#pragma unroll
  for (int m = 0; m < 4; ++m)
#pragma unroll
    for (int n = 0; n < 4; ++n)
      acc[m][n] = (f32x4){0.f, 0.f, 0.f, 0.f};

  for (int t = 0; t < KTILES; ++t) {
    const int cur = t & 1;
    const short* Ab = As[cur];
    const short* Bb = Bs[cur];

    // ---- phase 0: stage t+1 early, read A(m0,m1) + all B, 16 MFMA
    if (t + 1 < KTILES) stage(cur ^ 1, t + 1);
    bf16x8 bf[4][2];
#pragma unroll
    for (int n = 0; n < 4; ++n) {
      bf[n][0] = *(const bf16x8*)&Bb[(brow + n * 16) * 64 + swz0];
      bf[n][1] = *(const bf16x8*)&Bb[(brow + n * 16) * 64 + swz1];
    }
    bf16x8 af[2][2];
#pragma unroll
    for (int mm = 0; mm < 2; ++mm) {
      af[mm][0] = *(const bf16x8*)&Ab[(arow + mm * 16) * 64 + swz0];
      af[mm][1] = *(const bf16x8*)&Ab[(arow + mm * 16) * 64 + swz1];
    }
    __builtin_amdgcn_s_barrier();
    asm volatile("s_waitcnt lgkmcnt(0)");
    __builtin_amdgcn_s_setprio(1);
#pragma unroll
    for (int mm = 0; mm < 2; ++mm)
#pragma unroll
      for (int n = 0; n < 4; ++n)
#pragma unroll
        for (int ks = 0; ks < 2; ++ks)
          acc[mm][n] = __builtin_amdgcn_mfma_f32_16x16x32_bf16(
              af[mm][ks], bf[n][ks], acc[mm][n], 0, 0, 0);
    __builtin_amdgcn_s_setprio(0);
    __builtin_amdgcn_s_barrier();

    // ---- phase 1: read A(m2,m3), 16 MFMA (B reused from regs)
#pragma unroll
    for (int mm = 0; mm < 2; ++mm) {
      af[mm][0] = *(const bf16x8*)&Ab[(arow + (2 + mm) * 16) * 64 + swz0];
      af[mm][1] = *(const bf16x8*)&Ab[(arow + (2 + mm) * 16) * 64 + swz1];
    }
    __builtin_amdgcn_s_barrier();
    asm volatile("s_waitcnt lgkmcnt(0)");
    __builtin_amdgcn_s_setprio(1);
#pragma unroll
    for (int mm = 0; mm < 2; ++mm)
#pragma unroll
      for (int n = 0; n < 4; ++n)
#pragma unroll
        for (int ks = 0; ks < 2; ++ks)
          acc[2 + mm][n] = __builtin_amdgcn_mfma_f32_16x16x32_bf16(
              af[mm][ks], bf[n][ks], acc[2 + mm][n], 0, 0, 0);
    __builtin_amdgcn_s_setprio(0);
    __builtin_amdgcn_s_barrier();

    // ---- expert boundary: Horner rescale acc *= c'_e/c'_{e+1} (e=7: *= c'_7)
    if ((t & 7) == 7) {
      const int e = t >> 3;
#pragma unroll
      for (int m = 0; m < 4; ++m)
#pragma unroll
        for (int r = 0; r < 4; ++r) {
          float rr = cfr[(wm * 64 + m * 16 + lhi * 4 + r) * NE + e];
#pragma unroll
          for (int n = 0; n < 4; ++n)
            acc[m][n][r] *= rr;
        }
    }

    // ---- tile boundary: t+1's 6 gloads (issued at p0, ~2 phases ago) must land
    if (t + 1 < KTILES) {
      asm volatile("s_waitcnt vmcnt(0)");
      __builtin_amdgcn_s_barrier();
    }
  }

  // ---- epilogue: out = acc + sum_e coef[n,e]*bias[e,o]
  float bcol[4][NE];
#pragma unroll
  for (int n = 0; n < 4; ++n) {
    const int cg = col0 + wn * 64 + n * 16 + llo;
#pragma unroll
    for (int e = 0; e < NE; ++e) bcol[n][e] = bias[e * COUT + cg];
  }
#pragma unroll
  for (int m = 0; m < 4; ++m)
#pragma unroll
    for (int r = 0; r < 4; ++r) {
      const int rl = wm * 64 + m * 16 + lhi * 4 + r;
      float cv[NE];
#pragma unroll
      for (int e = 0; e < NE; ++e) cv[e] = cfc[rl * NE + e];
      float* orow = out + (size_t)(row0 + rl) * COUT;
#pragma unroll
      for (int n = 0; n < 4; ++n) {
        float bm = 0.f;
#pragma unroll
        for (int e = 0; e < NE; ++e) bm += cv[e] * bcol[n][e];
        orow[col0 + wn * 64 + n * 16 + llo] = acc[m][n][r] + bm;
      }
    }
}

extern "C" void kernel_launch(void* const* d_in, const int* in_sizes, int n_in,
                              void* d_out, int out_size, void* d_ws, size_t ws_size,
                              hipStream_t stream) {
  const float* x    = (const float*)d_in[0];  // [16384][512]
  const float* coef = (const float*)d_in[1];  // [16384][8]
  const float* w    = (const float*)d_in[2];  // [8][512][512]
  const float* bias = (const float*)d_in[3];  // [8][512]
  float* out = (float*)d_out;

  short* xb = (short*)d_ws;                   // 16 MB bf16 x
  short* wb = xb + (size_t)N_TOK * CIN;       // 4 MB bf16 weight

  const int NX = N_TOK * CIN / 4, NW = NE * COUT * CIN / 4;
  cvt_all<<<(NX + NW) / 256, 256, 0, stream>>>(
      (const float4*)x, (const float4*)w, (s16x4*)xb, (s16x4*)wb);

  moe_gemm<<<(N_TOK / BM) * (COUT / BN), 512, 0, stream>>>(xb, wb, coef, bias, out);
}